// Round 6
// baseline (113.030 us; speedup 1.0000x reference)
//
#include <hip/hip_runtime.h>
#include <math.h>

#define D_DIM 160
#define H_DIM 192
#define W_DIM 192
#define HWN   (H_DIM * W_DIM)                 // 36864
#define NTOT  ((size_t)D_DIM * H_DIM * W_DIM) // 5898240

#define C1 0.0001f   // 0.01^2
#define C2 0.0009f   // 0.03^2

#define HSEG 12                    // output rows per wave
#define NHSEG (H_DIM / HSEG)       // 16
#define NWAVES (NHSEG * 3 * D_DIM) // 7680
#define MARCH (HSEG + 10)          // 22 input rows per wave

#define DC 22                      // pass2 d-outputs per block
#define DCHUNKS 8                  // 8*22 = 176 >= 160

struct GaussW { float g[11]; };

// Pass 1 v5: fully-unrolled (template recursion) H-march. Row J:
//   stage (x,y) row in LDS -> 11-tap W-blur of the 5 products ->
//   accumulate into acc[f][o] for o = J-10..J (ALL indices constexpr ->
//   guaranteed SSA/VGPR, no shift moves, no runtime-indexed arrays).
template<int J>
__device__ __forceinline__ void p1_steps(
    const float* __restrict__ pa1, const float* __restrict__ pa2,
    const float* __restrict__ pb1, const float* __restrict__ pb2,
    float* __restrict__ ep, float2* __restrict__ srow,
    const int lane, const bool va, const bool vb,
    const int hbase, const GaussW& gw, float (&acc)[5][HSEG])
{
    if constexpr (J < MARCH) {
        const int hin = hbase - 5 + J;
        if (hin >= 0 && hin < H_DIM) {          // wave-uniform
            float2 v;
            v.x = va ? pa1[J * W_DIM] : 0.f;
            v.y = va ? pa2[J * W_DIM] : 0.f;
            srow[lane] = v;
            if (lane < 10) {
                float2 u;
                u.x = vb ? pb1[J * W_DIM] : 0.f;
                u.y = vb ? pb2[J * W_DIM] : 0.f;
                srow[64 + lane] = u;
            }
            __builtin_amdgcn_wave_barrier();

            float a0 = 0.f, a1 = 0.f, a2 = 0.f, a3 = 0.f, a4 = 0.f;
#pragma unroll
            for (int k = 0; k < 11; ++k) {
                float2 p = srow[lane + k];
                float t1 = gw.g[k] * p.x;
                float t2 = gw.g[k] * p.y;
                a0 += t1;
                a1 += t2;
                a2 = fmaf(t1, p.x, a2);
                a3 = fmaf(t2, p.y, a3);
                a4 = fmaf(t1, p.y, a4);
            }
            __builtin_amdgcn_wave_barrier();

            // row J feeds outputs o = J-10 .. J with weight g[J-o]
#pragma unroll
            for (int t = 0; t < 11; ++t) {
                const int o = J - 10 + t;       // constexpr after unroll
                if (o >= 0 && o < HSEG) {
                    const float wgt = gw.g[10 - t];
                    acc[0][o] = fmaf(wgt, a0, acc[0][o]);
                    acc[1][o] = fmaf(wgt, a1, acc[1][o]);
                    acc[2][o] = fmaf(wgt, a2, acc[2][o]);
                    acc[3][o] = fmaf(wgt, a3, acc[3][o]);
                    acc[4][o] = fmaf(wgt, a4, acc[4][o]);
                }
            }
        }

        // output row o = J-10 is complete after step J
        if constexpr (J >= 10) {
            constexpr int o = J - 10;
            const size_t rb = (size_t)o * W_DIM;
            ep[rb]            = acc[0][o];
            ep[NTOT + rb]     = acc[1][o];
            ep[2 * NTOT + rb] = acc[2][o];
            ep[3 * NTOT + rb] = acc[3][o];
            ep[4 * NTOT + rb] = acc[4][o];
        }

        p1_steps<J + 1>(pa1, pa2, pb1, pb2, ep, srow, lane, va, vb,
                        hbase, gw, acc);
    }
}

__global__ __launch_bounds__(256, 2) void ssim_pass1(
    const float* __restrict__ img1, const float* __restrict__ img2,
    float* __restrict__ fields, GaussW gw)
{
    __shared__ float2 sxy[4][80];

    const int wv   = threadIdx.x >> 6;
    const int lane = threadIdx.x & 63;
    const int wid  = blockIdx.x * 4 + wv;
    const int hseg = wid & (NHSEG - 1);     // wid % 16
    const int t    = wid >> 4;
    const int wtile = t % 3;
    const int d     = t / 3;
    const int w0    = wtile * 64;
    const int hbase = hseg * HSEG;

    const int  cola = w0 - 5 + lane;                 // stage col 1
    const bool va   = (cola >= 0) && (cola < W_DIM);
    const int  colb = w0 + 59 + lane;                // stage col 2 (lane<10)
    const bool vb   = (lane < 10) && (colb < W_DIM);
    const int  colac = min(max(cola, 0), W_DIM - 1); // clamped (masked lanes)
    const int  colbc = min(colb, W_DIM - 1);

    const size_t plane  = (size_t)d * HWN;
    const long   rowoff = (long)(hbase - 5) * W_DIM;
    const float* pa1 = img1 + plane + rowoff + colac;
    const float* pa2 = img2 + plane + rowoff + colac;
    const float* pb1 = img1 + plane + rowoff + colbc;
    const float* pb2 = img2 + plane + rowoff + colbc;

    float acc[5][HSEG];
#pragma unroll
    for (int f = 0; f < 5; ++f)
#pragma unroll
        for (int o = 0; o < HSEG; ++o) acc[f][o] = 0.f;

    float* ep = fields + plane + (size_t)hbase * W_DIM + (w0 + lane);

    p1_steps<0>(pa1, pa2, pb1, pb2, ep, sxy[wv], lane, va, vb, hbase, gw, acc);
}

// Pass 2: rolling-window D-blur + SSIM + block reduce -> double atomic.
__global__ __launch_bounds__(256) void ssim_pass2(
    const float* __restrict__ fields, double* __restrict__ accum, GaussW gwts)
{
    const int hw = blockIdx.x * 256 + threadIdx.x;
    const int d0 = blockIdx.y * DC;

    float win[5][11];
#pragma unroll
    for (int i = 0; i < 10; ++i) {
        int p = d0 - 5 + i;
        bool ok = (p >= 0) && (p < D_DIM);
        size_t off = (size_t)(ok ? p : 0) * HWN + hw;
#pragma unroll
        for (int f = 0; f < 5; ++f)
            win[f][i] = ok ? fields[(size_t)f * NTOT + off] : 0.f;
    }

    float ssum = 0.f;
#pragma unroll
    for (int j = 0; j < DC; ++j) {
        const int d = d0 + j;
        {
            int p = d + 5;
            bool ok = (p < D_DIM);
            size_t off = (size_t)(ok ? p : 0) * HWN + hw;
#pragma unroll
            for (int f = 0; f < 5; ++f)
                win[f][(j + 10) % 11] = ok ? fields[(size_t)f * NTOT + off] : 0.f;
        }
        if (d < D_DIM) {
            float m[5];
#pragma unroll
            for (int f = 0; f < 5; ++f) {
                float acc = 0.f;
#pragma unroll
                for (int k = 0; k < 11; ++k)
                    acc += gwts.g[k] * win[f][(j + k) % 11];
                m[f] = acc;
            }
            float mu1sq = m[0] * m[0];
            float mu2sq = m[1] * m[1];
            float mu12  = m[0] * m[1];
            float s1sq  = m[2] - mu1sq;
            float s2sq  = m[3] - mu2sq;
            float s12   = m[4] - mu12;
            ssum += ((2.f * mu12 + C1) * (2.f * s12 + C2)) /
                    ((mu1sq + mu2sq + C1) * (s1sq + s2sq + C2));
        }
    }

    for (int off = 32; off > 0; off >>= 1)
        ssum += __shfl_down(ssum, off, 64);
    __shared__ float wsum[4];
    int lane = threadIdx.x & 63;
    int wvx  = threadIdx.x >> 6;
    if (lane == 0) wsum[wvx] = ssum;
    __syncthreads();
    if (threadIdx.x == 0) {
        float bs = wsum[0] + wsum[1] + wsum[2] + wsum[3];
        atomicAdd(accum, (double)bs);
    }
}

__global__ void ssim_finalize(const double* __restrict__ accum,
                              float* __restrict__ out)
{
    out[0] = (float)(accum[0] / (double)NTOT);
}

extern "C" void kernel_launch(void* const* d_in, const int* in_sizes, int n_in,
                              void* d_out, int out_size, void* d_ws, size_t ws_size,
                              hipStream_t stream)
{
    const float* img1 = (const float*)d_in[0];
    const float* img2 = (const float*)d_in[1];
    float* out = (float*)d_out;

    GaussW gwts;
    {
        double raw[11], sum = 0.0;
        for (int i = 0; i < 11; ++i) {
            double x = (double)i - 5.0;
            raw[i] = exp(-(x * x) / (2.0 * 1.5 * 1.5));
            sum += raw[i];
        }
        for (int i = 0; i < 11; ++i) gwts.g[i] = (float)(raw[i] / sum);
    }

    float* fields = (float*)d_ws;                          // 5 * NTOT floats
    double* accum = (double*)((char*)d_ws + 5 * NTOT * 4); // 8B, 8-aligned

    hipMemsetAsync(accum, 0, sizeof(double), stream);

    ssim_pass1<<<NWAVES / 4, 256, 0, stream>>>(img1, img2, fields, gwts);

    dim3 g2(HWN / 256, DCHUNKS); // (144, 8)
    ssim_pass2<<<g2, 256, 0, stream>>>(fields, accum, gwts);

    ssim_finalize<<<1, 1, 0, stream>>>(accum, out);
}

// Round 7
// 90.792 us; speedup vs baseline: 1.2449x; 1.2449x over previous
//
#include <hip/hip_runtime.h>
#include <math.h>

#define D_DIM 160
#define H_DIM 192
#define W_DIM 192
#define HWN   (H_DIM * W_DIM)                 // 36864
#define NTOT  ((size_t)D_DIM * H_DIM * W_DIM) // 5898240

#define C1 0.0001f   // 0.01^2
#define C2 0.0009f   // 0.03^2

#define HSEG 16                    // output rows per wave
#define NHSEG (H_DIM / HSEG)       // 12
#define NWAVES (NHSEG * 3 * D_DIM) // 5760
#define MARCH (HSEG + 10)          // 26 input rows per wave

#define DC 22                      // pass2 d-outputs per block
#define DCHUNKS 8                  // 8*22 = 176 >= 160

struct GaussW { float g[11]; };

__device__ __forceinline__ int clampi(int v, int lo, int hi) {
    return min(max(v, lo), hi);
}

// Pass 1 v6: fully-unrolled H-march with DEPTH-2 REGISTER PREFETCH of the
// global rows. Step J: issue loads for row J+2 (stay in flight across the
// wave_barrier fences -> latency hidden under 2 steps of work), ds_write
// row J from registers loaded 2 steps ago, 11-tap W-blur from LDS,
// accumulate into constexpr-indexed acc (register-resident, VGPR=84 in R6).
template<int J>
__device__ __forceinline__ void p1_steps(
    const float* __restrict__ pa1, const float* __restrict__ pa2,
    const float* __restrict__ pb1, const float* __restrict__ pb2,
    float* __restrict__ ep, float2* __restrict__ srow,
    const int lane, const bool va, const bool vb,
    const int hbase, const GaussW& gw, float (&acc)[5][HSEG],
    float2 cur_v, float2 cur_u, float2 nxt_v, float2 nxt_u)
{
    if constexpr (J < MARCH) {
        // issue prefetch for row J+2 (before any fence; in flight 2 steps)
        float2 pf_v = {0.f, 0.f}, pf_u = {0.f, 0.f};
        if constexpr (J + 2 < MARCH) {
            const int hc = clampi(hbase - 5 + J + 2, 0, H_DIM - 1);
            const size_t ro = (size_t)hc * W_DIM;
            pf_v.x = pa1[ro];
            pf_v.y = pa2[ro];
            pf_u.x = pb1[ro];
            pf_u.y = pb2[ro];
        }

        const int hin = hbase - 5 + J;
        if (hin >= 0 && hin < H_DIM) {          // wave-uniform
            __builtin_amdgcn_wave_barrier();    // fence vs prev step's reads
            float2 zz = {0.f, 0.f};
            srow[lane] = va ? cur_v : zz;
            if (lane < 10) srow[64 + lane] = vb ? cur_u : zz;
            __builtin_amdgcn_wave_barrier();    // fence write -> reads

            float a0 = 0.f, a1 = 0.f, a2 = 0.f, a3 = 0.f, a4 = 0.f;
#pragma unroll
            for (int k = 0; k < 11; ++k) {
                float2 p = srow[lane + k];
                float t1 = gw.g[k] * p.x;
                float t2 = gw.g[k] * p.y;
                a0 += t1;
                a1 += t2;
                a2 = fmaf(t1, p.x, a2);
                a3 = fmaf(t2, p.y, a3);
                a4 = fmaf(t1, p.y, a4);
            }

            // row J feeds outputs o = J-10 .. J with weight g[J-o]
#pragma unroll
            for (int t = 0; t < 11; ++t) {
                const int o = J - 10 + t;       // constexpr after unroll
                if (o >= 0 && o < HSEG) {
                    const float wgt = gw.g[10 - t];
                    acc[0][o] = fmaf(wgt, a0, acc[0][o]);
                    acc[1][o] = fmaf(wgt, a1, acc[1][o]);
                    acc[2][o] = fmaf(wgt, a2, acc[2][o]);
                    acc[3][o] = fmaf(wgt, a3, acc[3][o]);
                    acc[4][o] = fmaf(wgt, a4, acc[4][o]);
                }
            }
        }

        // output row o = J-10 complete after step J
        if constexpr (J >= 10) {
            constexpr int o = J - 10;
            const size_t rb = (size_t)o * W_DIM;
            ep[rb]            = acc[0][o];
            ep[NTOT + rb]     = acc[1][o];
            ep[2 * NTOT + rb] = acc[2][o];
            ep[3 * NTOT + rb] = acc[3][o];
            ep[4 * NTOT + rb] = acc[4][o];
        }

        p1_steps<J + 1>(pa1, pa2, pb1, pb2, ep, srow, lane, va, vb,
                        hbase, gw, acc, nxt_v, nxt_u, pf_v, pf_u);
    }
}

__global__ __launch_bounds__(256, 2) void ssim_pass1(
    const float* __restrict__ img1, const float* __restrict__ img2,
    float* __restrict__ fields, GaussW gw)
{
    __shared__ float2 sxy[4][80];

    const int wv   = threadIdx.x >> 6;
    const int lane = threadIdx.x & 63;
    const int wid  = blockIdx.x * 4 + wv;
    const int hseg = wid % NHSEG;
    const int t    = wid / NHSEG;
    const int wtile = t % 3;
    const int d     = t / 3;
    const int w0    = wtile * 64;
    const int hbase = hseg * HSEG;

    const int  cola = w0 - 5 + lane;                 // stage col 1
    const bool va   = (cola >= 0) && (cola < W_DIM);
    const int  colb = w0 + 59 + lane;                // stage col 2 (lane<10)
    const bool vb   = (lane < 10) && (colb < W_DIM);
    const int  colac = clampi(cola, 0, W_DIM - 1);   // clamped (masked lanes)
    const int  colbc = min(colb, W_DIM - 1);

    const size_t plane = (size_t)d * HWN;
    const float* pa1 = img1 + plane + colac;
    const float* pa2 = img2 + plane + colac;
    const float* pb1 = img1 + plane + colbc;
    const float* pb2 = img2 + plane + colbc;

    float acc[5][HSEG];
#pragma unroll
    for (int f = 0; f < 5; ++f)
#pragma unroll
        for (int o = 0; o < HSEG; ++o) acc[f][o] = 0.f;

    // prologue: load rows 0 and 1 into the pipeline registers
    float2 v0, u0, v1, u1;
    {
        const int hc0 = clampi(hbase - 5, 0, H_DIM - 1);
        const size_t r0 = (size_t)hc0 * W_DIM;
        v0.x = pa1[r0]; v0.y = pa2[r0];
        u0.x = pb1[r0]; u0.y = pb2[r0];
        const int hc1 = clampi(hbase - 4, 0, H_DIM - 1);
        const size_t r1 = (size_t)hc1 * W_DIM;
        v1.x = pa1[r1]; v1.y = pa2[r1];
        u1.x = pb1[r1]; u1.y = pb2[r1];
    }

    float* ep = fields + plane + (size_t)hbase * W_DIM + (w0 + lane);

    p1_steps<0>(pa1, pa2, pb1, pb2, ep, sxy[wv], lane, va, vb, hbase, gw,
                acc, v0, u0, v1, u1);
}

// Pass 2: rolling-window D-blur + SSIM + block reduce -> double atomic.
__global__ __launch_bounds__(256) void ssim_pass2(
    const float* __restrict__ fields, double* __restrict__ accum, GaussW gwts)
{
    const int hw = blockIdx.x * 256 + threadIdx.x;
    const int d0 = blockIdx.y * DC;

    float win[5][11];
#pragma unroll
    for (int i = 0; i < 10; ++i) {
        int p = d0 - 5 + i;
        bool ok = (p >= 0) && (p < D_DIM);
        size_t off = (size_t)(ok ? p : 0) * HWN + hw;
#pragma unroll
        for (int f = 0; f < 5; ++f)
            win[f][i] = ok ? fields[(size_t)f * NTOT + off] : 0.f;
    }

    float ssum = 0.f;
#pragma unroll
    for (int j = 0; j < DC; ++j) {
        const int d = d0 + j;
        {
            int p = d + 5;
            bool ok = (p < D_DIM);
            size_t off = (size_t)(ok ? p : 0) * HWN + hw;
#pragma unroll
            for (int f = 0; f < 5; ++f)
                win[f][(j + 10) % 11] = ok ? fields[(size_t)f * NTOT + off] : 0.f;
        }
        if (d < D_DIM) {
            float m[5];
#pragma unroll
            for (int f = 0; f < 5; ++f) {
                float acc = 0.f;
#pragma unroll
                for (int k = 0; k < 11; ++k)
                    acc += gwts.g[k] * win[f][(j + k) % 11];
                m[f] = acc;
            }
            float mu1sq = m[0] * m[0];
            float mu2sq = m[1] * m[1];
            float mu12  = m[0] * m[1];
            float s1sq  = m[2] - mu1sq;
            float s2sq  = m[3] - mu2sq;
            float s12   = m[4] - mu12;
            ssum += ((2.f * mu12 + C1) * (2.f * s12 + C2)) /
                    ((mu1sq + mu2sq + C1) * (s1sq + s2sq + C2));
        }
    }

    for (int off = 32; off > 0; off >>= 1)
        ssum += __shfl_down(ssum, off, 64);
    __shared__ float wsum[4];
    int lane = threadIdx.x & 63;
    int wvx  = threadIdx.x >> 6;
    if (lane == 0) wsum[wvx] = ssum;
    __syncthreads();
    if (threadIdx.x == 0) {
        float bs = wsum[0] + wsum[1] + wsum[2] + wsum[3];
        atomicAdd(accum, (double)bs);
    }
}

__global__ void ssim_finalize(const double* __restrict__ accum,
                              float* __restrict__ out)
{
    out[0] = (float)(accum[0] / (double)NTOT);
}

extern "C" void kernel_launch(void* const* d_in, const int* in_sizes, int n_in,
                              void* d_out, int out_size, void* d_ws, size_t ws_size,
                              hipStream_t stream)
{
    const float* img1 = (const float*)d_in[0];
    const float* img2 = (const float*)d_in[1];
    float* out = (float*)d_out;

    GaussW gwts;
    {
        double raw[11], sum = 0.0;
        for (int i = 0; i < 11; ++i) {
            double x = (double)i - 5.0;
            raw[i] = exp(-(x * x) / (2.0 * 1.5 * 1.5));
            sum += raw[i];
        }
        for (int i = 0; i < 11; ++i) gwts.g[i] = (float)(raw[i] / sum);
    }

    float* fields = (float*)d_ws;                          // 5 * NTOT floats
    double* accum = (double*)((char*)d_ws + 5 * NTOT * 4); // 8B, 8-aligned

    hipMemsetAsync(accum, 0, sizeof(double), stream);

    ssim_pass1<<<NWAVES / 4, 256, 0, stream>>>(img1, img2, fields, gwts);

    dim3 g2(HWN / 256, DCHUNKS); // (144, 8)
    ssim_pass2<<<g2, 256, 0, stream>>>(fields, accum, gwts);

    ssim_finalize<<<1, 1, 0, stream>>>(accum, out);
}